// Round 4
// baseline (212.348 us; speedup 1.0000x reference)
//
#include <hip/hip_runtime.h>

#define S_LEN 4096
#define NROWS 16384   // B*S

typedef __attribute__((ext_vector_type(8))) __bf16 bf16x8;
typedef __attribute__((ext_vector_type(8))) unsigned short ushort8;
typedef __attribute__((ext_vector_type(4))) float floatx4;

__device__ __forceinline__ unsigned short f2bf(float f) {   // RNE
    unsigned int u = __float_as_uint(f);
    unsigned int r = (u + 0x7fffu + ((u >> 16) & 1u)) >> 16;
    return (unsigned short)r;
}

__device__ __forceinline__ bf16x8 cvt_bf16x8(float4 a, float4 b) {
    union { ushort8 u; bf16x8 v; } r;
    r.u[0] = f2bf(a.x); r.u[1] = f2bf(a.y); r.u[2] = f2bf(a.z); r.u[3] = f2bf(a.w);
    r.u[4] = f2bf(b.x); r.u[5] = f2bf(b.y); r.u[6] = f2bf(b.z); r.u[7] = f2bf(b.w);
    return r.v;
}

// ---------------- K0: weights fp32 -> bf16 transposed (unchanged from R2)
__global__ __launch_bounds__(256) void convw_kernel(
    const float* __restrict__ Wq, const float* __restrict__ Wk,
    const float* __restrict__ Wv, const float* __restrict__ Wo,
    unsigned short* __restrict__ WqT, unsigned short* __restrict__ WkT,
    unsigned short* __restrict__ WvT, unsigned short* __restrict__ WoT)
{
    int tid = blockIdx.x * 256 + threadIdx.x;   // 0..32767
    int n = tid >> 9, k = tid & 511;            // (n<64, k<512)
    WqT[tid] = f2bf(Wq[k * 64 + n]);
    WkT[tid] = f2bf(Wk[k * 64 + n]);
    WvT[tid] = f2bf(Wv[k * 64 + n]);
    int n2 = tid >> 6, k2 = tid & 63;           // (n2<512, k2<64)
    WoT[tid] = f2bf(Wo[k2 * 512 + n2]);
}

// ---------------- K1: QKV projection, R2 dataflow split by OUTPUT MATRIX.
// grid (3, 1024): blockIdx.x = which matrix (Q/K/V), blockIdx.y = 16-row tile.
// Per-wave code identical to the R2-passing kernel, restricted to one matrix.
__global__ __launch_bounds__(64) void qkv_kernel(
    const float* __restrict__ x,
    const unsigned short* __restrict__ WqT, const unsigned short* __restrict__ WkT,
    const unsigned short* __restrict__ WvT,
    const float* __restrict__ bq, const float* __restrict__ bk, const float* __restrict__ bv,
    unsigned short* __restrict__ Qb, unsigned short* __restrict__ Kb,
    unsigned short* __restrict__ Vt)
{
    const int m = blockIdx.x;            // 0=Q, 1=K, 2=V (m fastest: x-tile stays L2-hot)
    const int row0 = blockIdx.y * 16;
    const int lane = threadIdx.x, cl = lane & 15, quad = lane >> 4;
    const unsigned short* WT = (m == 0) ? WqT : (m == 1) ? WkT : WvT;
    const float* bias = (m == 0) ? bq : (m == 1) ? bk : bv;

    floatx4 acc[4];
    #pragma unroll
    for (int t = 0; t < 4; t++) acc[t] = (floatx4){0.f, 0.f, 0.f, 0.f};
    const float* xrow = x + (size_t)(row0 + cl) * 512;
    #pragma unroll 2
    for (int kc = 0; kc < 16; kc++) {
        const int k0 = kc * 32 + quad * 8;
        float4 xa = *(const float4*)(xrow + k0);
        float4 xb = *(const float4*)(xrow + k0 + 4);
        bf16x8 af = cvt_bf16x8(xa, xb);
        #pragma unroll
        for (int t = 0; t < 4; t++) {
            bf16x8 bf = *(const bf16x8*)(const void*)(WT + (t * 16 + cl) * 512 + k0);
            acc[t] = __builtin_amdgcn_mfma_f32_16x16x32_bf16(af, bf, acc[t], 0, 0, 0);
        }
    }
    if (m < 2) {
        unsigned short* outp = (m == 0) ? Qb : Kb;
        #pragma unroll
        for (int t = 0; t < 4; t++) {
            const int d = t * 16 + cl;
            const float bd = bias[d];
            #pragma unroll
            for (int r = 0; r < 4; r++)
                outp[(size_t)(row0 + quad * 4 + r) * 64 + d] = f2bf(acc[t][r] + bd);
        }
    } else {
        const int b = row0 >> 12, s_base = row0 & 4095;
        #pragma unroll
        for (int t = 0; t < 4; t++) {
            const int d = t * 16 + cl;
            const float bd = bias[d];
            #pragma unroll
            for (int r = 0; r < 4; r++)
                Vt[((size_t)b * 64 + d) * S_LEN + s_base + quad * 4 + r] = f2bf(acc[t][r] + bd);
        }
    }
}

// ---------------- K2: causal flash attention. R2 numerics (running max, alpha,
// RNE f2bf, -1e30 mask, R2 merge) + hoisted fragment loads + per-lane l
// accumulation (alpha is row-uniform, so l = l*alpha + sum_t p is exact; one
// cross-lane reduce at the end replaces the per-tile sum shuffle-tree).
__global__ __launch_bounds__(256, 4) void attn_kernel(
    const unsigned short* __restrict__ Qb, const unsigned short* __restrict__ Kb,
    const unsigned short* __restrict__ Vt, unsigned short* __restrict__ Ob)
{
    __shared__ unsigned short Ps[4][16 * 72];
    __shared__ float Op[4][16][66];
    __shared__ float Ml[4][16][2];
    const int bid = blockIdx.x;              // 0..1023
    const int qt = 255 - (bid >> 2);         // longest-first (LPT)
    const int b = bid & 3;
    const int q0 = qt * 16;
    const int nkt = (qt >> 2) + 1;           // 64-key tiles in causal range
    const int tid = threadIdx.x;
    const int w = tid >> 6, lane = tid & 63, cl = lane & 15, quad = lane >> 4;

    const size_t qrow = (size_t)b * S_LEN + q0 + cl;
    const bf16x8 aq0 = *(const bf16x8*)(const void*)(Qb + qrow * 64 + quad * 8);
    const bf16x8 aq1 = *(const bf16x8*)(const void*)(Qb + qrow * 64 + 32 + quad * 8);
    const unsigned short* kbb = Kb + (size_t)b * S_LEN * 64;
    const unsigned short* vbb = Vt + (size_t)b * 64 * S_LEN;

    float mrow[4], lrow[4];
    floatx4 Oacc[4];
    #pragma unroll
    for (int r = 0; r < 4; r++) { mrow[r] = -1e30f; lrow[r] = 0.f; }
    #pragma unroll
    for (int u = 0; u < 4; u++) Oacc[u] = (floatx4){0.f, 0.f, 0.f, 0.f};

    const float C2 = 0.022542110013890054f;  // log2(e)/sqrt(4096)
    unsigned short* Pw = Ps[w];

    for (int jt = w; jt < nkt; jt += 4) {
        const int j0 = jt * 64;
        // hoisted fragment loads: latency hides under QK-MFMA + softmax
        bf16x8 kf[4][2], vf[4][2];
        #pragma unroll
        for (int t = 0; t < 4; t++) {
            const unsigned short* kp = kbb + (size_t)(j0 + t * 16 + cl) * 64 + quad * 8;
            kf[t][0] = *(const bf16x8*)(const void*)kp;
            kf[t][1] = *(const bf16x8*)(const void*)(kp + 32);
        }
        #pragma unroll
        for (int u = 0; u < 4; u++) {
            const unsigned short* vp = vbb + (size_t)(u * 16 + cl) * S_LEN + j0 + quad * 8;
            vf[u][0] = *(const bf16x8*)(const void*)vp;
            vf[u][1] = *(const bf16x8*)(const void*)(vp + 32);
        }
        // S = Q K^T
        float z[4][4];
        #pragma unroll
        for (int t = 0; t < 4; t++) {
            floatx4 acc = (floatx4){0.f, 0.f, 0.f, 0.f};
            acc = __builtin_amdgcn_mfma_f32_16x16x32_bf16(aq0, kf[t][0], acc, 0, 0, 0);
            acc = __builtin_amdgcn_mfma_f32_16x16x32_bf16(aq1, kf[t][1], acc, 0, 0, 0);
            #pragma unroll
            for (int r = 0; r < 4; r++) z[t][r] = acc[r] * C2;
        }
        if (jt == nkt - 1) {  // only the last tile crosses the diagonal
            #pragma unroll
            for (int t = 0; t < 4; t++)
                #pragma unroll
                for (int r = 0; r < 4; r++)
                    if (j0 + t * 16 + cl > q0 + quad * 4 + r) z[t][r] = -1e30f;
        }
        // running max (cross-lane tree) + alpha
        float alpha[4], p[4][4];
        #pragma unroll
        for (int r = 0; r < 4; r++) {
            float v = fmaxf(fmaxf(z[0][r], z[1][r]), fmaxf(z[2][r], z[3][r]));
            v = fmaxf(v, __shfl_xor(v, 1, 64));
            v = fmaxf(v, __shfl_xor(v, 2, 64));
            v = fmaxf(v, __shfl_xor(v, 4, 64));
            v = fmaxf(v, __shfl_xor(v, 8, 64));
            float mn = fmaxf(mrow[r], v);
            alpha[r] = exp2f(mrow[r] - mn);
            mrow[r] = mn;
        }
        #pragma unroll
        for (int t = 0; t < 4; t++)
            #pragma unroll
            for (int r = 0; r < 4; r++) p[t][r] = exp2f(z[t][r] - mrow[r]);
        // per-lane l accumulation (alpha row-uniform -> exact); no sum tree here
        #pragma unroll
        for (int r = 0; r < 4; r++)
            lrow[r] = lrow[r] * alpha[r] + ((p[0][r] + p[1][r]) + (p[2][r] + p[3][r]));
        #pragma unroll
        for (int u = 0; u < 4; u++)
            #pragma unroll
            for (int r = 0; r < 4; r++) Oacc[u][r] *= alpha[r];

        // P: C-layout -> A-layout via wave-local LDS (R2-proven round trip)
        #pragma unroll
        for (int t = 0; t < 4; t++)
            #pragma unroll
            for (int r = 0; r < 4; r++)
                Pw[(quad * 4 + r) * 72 + t * 16 + cl] = f2bf(p[t][r]);
        asm volatile("s_waitcnt lgkmcnt(0)" ::: "memory");
        bf16x8 ap0 = *(const bf16x8*)(const void*)(Pw + cl * 72 + quad * 8);
        bf16x8 ap1 = *(const bf16x8*)(const void*)(Pw + cl * 72 + 32 + quad * 8);
        #pragma unroll
        for (int u = 0; u < 4; u++) {
            Oacc[u] = __builtin_amdgcn_mfma_f32_16x16x32_bf16(ap0, vf[u][0], Oacc[u], 0, 0, 0);
            Oacc[u] = __builtin_amdgcn_mfma_f32_16x16x32_bf16(ap1, vf[u][1], Oacc[u], 0, 0, 0);
        }
    }
    // one cross-lane l reduce (replaces per-tile sum trees)
    #pragma unroll
    for (int r = 0; r < 4; r++) {
        float s = lrow[r];
        s += __shfl_xor(s, 1, 64);
        s += __shfl_xor(s, 2, 64);
        s += __shfl_xor(s, 4, 64);
        s += __shfl_xor(s, 8, 64);
        lrow[r] = s;
    }
    // publish partials (R2 merge: m + l per wave, exp2 rescale)
    #pragma unroll
    for (int u = 0; u < 4; u++)
        #pragma unroll
        for (int r = 0; r < 4; r++)
            Op[w][quad * 4 + r][u * 16 + cl] = Oacc[u][r];
    if (cl == 0) {
        #pragma unroll
        for (int r = 0; r < 4; r++) {
            Ml[w][quad * 4 + r][0] = mrow[r];
            Ml[w][quad * 4 + r][1] = lrow[r];
        }
    }
    __syncthreads();
    {
        const int row = tid >> 4, d0 = (tid & 15) * 4;
        float m0 = Ml[0][row][0], m1 = Ml[1][row][0], m2 = Ml[2][row][0], m3 = Ml[3][row][0];
        float M = fmaxf(fmaxf(m0, m1), fmaxf(m2, m3));
        float s0 = exp2f(m0 - M), s1 = exp2f(m1 - M), s2 = exp2f(m2 - M), s3 = exp2f(m3 - M);
        float L = s0 * Ml[0][row][1] + s1 * Ml[1][row][1] + s2 * Ml[2][row][1] + s3 * Ml[3][row][1];
        float invL = 1.0f / L;
        unsigned short ov[4];
        #pragma unroll
        for (int i = 0; i < 4; i++) {
            float o = s0 * Op[0][row][d0 + i] + s1 * Op[1][row][d0 + i]
                    + s2 * Op[2][row][d0 + i] + s3 * Op[3][row][d0 + i];
            ov[i] = f2bf(o * invL);
        }
        *(uint2*)(void*)(Ob + ((size_t)b * S_LEN + q0 + row) * 64 + d0) = *(const uint2*)ov;
    }
}

// ---------------- K3: out = O @ Wo + bo via MFMA. 4 waves/block, wave = 16 rows x 128 cols.
__global__ __launch_bounds__(256) void oproj_kernel(
    const unsigned short* __restrict__ Ob, const unsigned short* __restrict__ WoT,
    const float* __restrict__ bo, float* __restrict__ out)
{
    const int row0 = blockIdx.x * 16;
    const int tid = threadIdx.x;
    const int w = tid >> 6, lane = tid & 63, cl = lane & 15, quad = lane >> 4;
    const unsigned short* op = Ob + (size_t)(row0 + cl) * 64 + quad * 8;
    const bf16x8 a0 = *(const bf16x8*)(const void*)op;
    const bf16x8 a1 = *(const bf16x8*)(const void*)(op + 32);
    #pragma unroll 2
    for (int i = 0; i < 8; i++) {
        const int n = w * 128 + i * 16 + cl;
        const unsigned short* wp = WoT + (size_t)n * 64 + quad * 8;
        bf16x8 b0 = *(const bf16x8*)(const void*)wp;
        bf16x8 b1 = *(const bf16x8*)(const void*)(wp + 32);
        floatx4 acc = (floatx4){0.f, 0.f, 0.f, 0.f};
        acc = __builtin_amdgcn_mfma_f32_16x16x32_bf16(a0, b0, acc, 0, 0, 0);
        acc = __builtin_amdgcn_mfma_f32_16x16x32_bf16(a1, b1, acc, 0, 0, 0);
        const float bod = bo[n];
        #pragma unroll
        for (int r = 0; r < 4; r++)
            out[(size_t)(row0 + quad * 4 + r) * 512 + n] = acc[r] + bod;
    }
}

extern "C" void kernel_launch(void* const* d_in, const int* in_sizes, int n_in,
                              void* d_out, int out_size, void* d_ws, size_t ws_size,
                              hipStream_t stream) {
    const float* x  = (const float*)d_in[0];
    const float* Wq = (const float*)d_in[1];
    const float* bq = (const float*)d_in[2];
    const float* Wk = (const float*)d_in[3];
    const float* bk = (const float*)d_in[4];
    const float* Wv = (const float*)d_in[5];
    const float* bv = (const float*)d_in[6];
    const float* Wo = (const float*)d_in[7];
    const float* bo = (const float*)d_in[8];
    float* out = (float*)d_out;

    unsigned short* Qb  = (unsigned short*)d_ws;               // 2 MB
    unsigned short* Kb  = Qb + (size_t)NROWS * 64;             // 2 MB
    unsigned short* Vt  = Kb + (size_t)NROWS * 64;             // 2 MB (transposed [b][64][s])
    unsigned short* Ob  = Vt + (size_t)NROWS * 64;             // 2 MB (bf16 O, row-major)
    unsigned short* WqT = Ob + (size_t)NROWS * 64;             // 64 KB each
    unsigned short* WkT = WqT + 512 * 64;
    unsigned short* WvT = WkT + 512 * 64;
    unsigned short* WoT = WvT + 512 * 64;

    convw_kernel<<<128, 256, 0, stream>>>(Wq, Wk, Wv, Wo, WqT, WkT, WvT, WoT);
    qkv_kernel<<<dim3(3, 1024), 64, 0, stream>>>(x, WqT, WkT, WvT, bq, bk, bv, Qb, Kb, Vt);
    attn_kernel<<<1024, 256, 0, stream>>>(Qb, Kb, Vt, Ob);
    oproj_kernel<<<NROWS / 16, 256, 0, stream>>>(Ob, WoT, bo, out);
}

// Round 5
// 202.755 us; speedup vs baseline: 1.0473x; 1.0473x over previous
//
#include <hip/hip_runtime.h>

#define S_LEN 4096
#define NROWS 16384   // B*S

typedef __attribute__((ext_vector_type(8))) __bf16 bf16x8;
typedef __attribute__((ext_vector_type(8))) unsigned short ushort8;
typedef __attribute__((ext_vector_type(4))) float floatx4;

__device__ __forceinline__ unsigned short f2bf(float f) {   // RNE
    unsigned int u = __float_as_uint(f);
    unsigned int r = (u + 0x7fffu + ((u >> 16) & 1u)) >> 16;
    return (unsigned short)r;
}

__device__ __forceinline__ bf16x8 cvt_bf16x8(float4 a, float4 b) {
    union { ushort8 u; bf16x8 v; } r;
    r.u[0] = f2bf(a.x); r.u[1] = f2bf(a.y); r.u[2] = f2bf(a.z); r.u[3] = f2bf(a.w);
    r.u[4] = f2bf(b.x); r.u[5] = f2bf(b.y); r.u[6] = f2bf(b.z); r.u[7] = f2bf(b.w);
    return r.v;
}

// ---------------- K0: weights fp32 -> bf16 transposed (unchanged, proven)
__global__ __launch_bounds__(256) void convw_kernel(
    const float* __restrict__ Wq, const float* __restrict__ Wk,
    const float* __restrict__ Wv, const float* __restrict__ Wo,
    unsigned short* __restrict__ WqT, unsigned short* __restrict__ WkT,
    unsigned short* __restrict__ WvT, unsigned short* __restrict__ WoT)
{
    int tid = blockIdx.x * 256 + threadIdx.x;   // 0..32767
    int n = tid >> 9, k = tid & 511;            // (n<64, k<512)
    WqT[tid] = f2bf(Wq[k * 64 + n]);
    WkT[tid] = f2bf(Wk[k * 64 + n]);
    WvT[tid] = f2bf(Wv[k * 64 + n]);
    int n2 = tid >> 6, k2 = tid & 63;           // (n2<512, k2<64)
    WoT[tid] = f2bf(Wo[k2 * 512 + n2]);
}

// ---------------- K1: QKV projection split by output matrix (unchanged, proven)
__global__ __launch_bounds__(64) void qkv_kernel(
    const float* __restrict__ x,
    const unsigned short* __restrict__ WqT, const unsigned short* __restrict__ WkT,
    const unsigned short* __restrict__ WvT,
    const float* __restrict__ bq, const float* __restrict__ bk, const float* __restrict__ bv,
    unsigned short* __restrict__ Qb, unsigned short* __restrict__ Kb,
    unsigned short* __restrict__ Vt)
{
    const int m = blockIdx.x;            // 0=Q, 1=K, 2=V
    const int row0 = blockIdx.y * 16;
    const int lane = threadIdx.x, cl = lane & 15, quad = lane >> 4;
    const unsigned short* WT = (m == 0) ? WqT : (m == 1) ? WkT : WvT;
    const float* bias = (m == 0) ? bq : (m == 1) ? bk : bv;

    floatx4 acc[4];
    #pragma unroll
    for (int t = 0; t < 4; t++) acc[t] = (floatx4){0.f, 0.f, 0.f, 0.f};
    const float* xrow = x + (size_t)(row0 + cl) * 512;
    #pragma unroll 2
    for (int kc = 0; kc < 16; kc++) {
        const int k0 = kc * 32 + quad * 8;
        float4 xa = *(const float4*)(xrow + k0);
        float4 xb = *(const float4*)(xrow + k0 + 4);
        bf16x8 af = cvt_bf16x8(xa, xb);
        #pragma unroll
        for (int t = 0; t < 4; t++) {
            bf16x8 bf = *(const bf16x8*)(const void*)(WT + (t * 16 + cl) * 512 + k0);
            acc[t] = __builtin_amdgcn_mfma_f32_16x16x32_bf16(af, bf, acc[t], 0, 0, 0);
        }
    }
    if (m < 2) {
        unsigned short* outp = (m == 0) ? Qb : Kb;
        #pragma unroll
        for (int t = 0; t < 4; t++) {
            const int d = t * 16 + cl;
            const float bd = bias[d];
            #pragma unroll
            for (int r = 0; r < 4; r++)
                outp[(size_t)(row0 + quad * 4 + r) * 64 + d] = f2bf(acc[t][r] + bd);
        }
    } else {
        const int b = row0 >> 12, s_base = row0 & 4095;
        #pragma unroll
        for (int t = 0; t < 4; t++) {
            const int d = t * 16 + cl;
            const float bd = bias[d];
            #pragma unroll
            for (int r = 0; r < 4; r++)
                Vt[((size_t)b * 64 + d) * S_LEN + s_base + quad * 4 + r] = f2bf(acc[t][r] + bd);
        }
    }
}

// ---------------- K2: causal flash attention, R4 numerics, 128-key strips.
// Each wave processes key-tile PAIRS (jt, jt+4): one max-tree / alpha /
// P-pack+drain per 128 keys instead of per 64, 2x independent work per
// chain stage. Leftover odd tile uses the proven single-tile path.
#define PSTR 152   // P-strip row stride (ushorts): 76 dwords -> 2-way bank aliasing (free)
__global__ __launch_bounds__(256, 2) void attn_kernel(
    const unsigned short* __restrict__ Qb, const unsigned short* __restrict__ Kb,
    const unsigned short* __restrict__ Vt, unsigned short* __restrict__ Ob)
{
    __shared__ unsigned short Ps[4][16 * PSTR];
    __shared__ float Op[4][16][66];
    __shared__ float Ml[4][16][2];
    const int bid = blockIdx.x;              // 0..1023
    const int qt = 255 - (bid >> 2);         // longest-first (LPT)
    const int b = bid & 3;
    const int q0 = qt * 16;
    const int nkt = (qt >> 2) + 1;           // 64-key tiles in causal range
    const int tid = threadIdx.x;
    const int w = tid >> 6, lane = tid & 63, cl = lane & 15, quad = lane >> 4;

    const size_t qrow = (size_t)b * S_LEN + q0 + cl;
    const bf16x8 aq0 = *(const bf16x8*)(const void*)(Qb + qrow * 64 + quad * 8);
    const bf16x8 aq1 = *(const bf16x8*)(const void*)(Qb + qrow * 64 + 32 + quad * 8);
    const unsigned short* kbb = Kb + (size_t)b * S_LEN * 64;
    const unsigned short* vbb = Vt + (size_t)b * 64 * S_LEN;

    float mrow[4], lrow[4];
    floatx4 Oacc[4];
    #pragma unroll
    for (int r = 0; r < 4; r++) { mrow[r] = -1e30f; lrow[r] = 0.f; }
    #pragma unroll
    for (int u = 0; u < 4; u++) Oacc[u] = (floatx4){0.f, 0.f, 0.f, 0.f};

    const float C2 = 0.022542110013890054f;  // log2(e)/sqrt(4096)
    unsigned short* Pw = Ps[w];

    int jt = w;
    // -------- paired 128-key strips --------
    for (; jt + 4 < nkt; jt += 8) {
        const int j0a = jt * 64, j0b = (jt + 4) * 64;
        float z[8][4];
        bf16x8 vf[8][2];
        // tile A: K frags + QK
        {
            bf16x8 kf[4][2];
            #pragma unroll
            for (int t = 0; t < 4; t++) {
                const unsigned short* kp = kbb + (size_t)(j0a + t * 16 + cl) * 64 + quad * 8;
                kf[t][0] = *(const bf16x8*)(const void*)kp;
                kf[t][1] = *(const bf16x8*)(const void*)(kp + 32);
            }
            #pragma unroll
            for (int t = 0; t < 4; t++) {
                floatx4 acc = (floatx4){0.f, 0.f, 0.f, 0.f};
                acc = __builtin_amdgcn_mfma_f32_16x16x32_bf16(aq0, kf[t][0], acc, 0, 0, 0);
                acc = __builtin_amdgcn_mfma_f32_16x16x32_bf16(aq1, kf[t][1], acc, 0, 0, 0);
                #pragma unroll
                for (int r = 0; r < 4; r++) z[t][r] = acc[r] * C2;
            }
        }
        #pragma unroll
        for (int u = 0; u < 4; u++) {
            const unsigned short* vp = vbb + (size_t)(u * 16 + cl) * S_LEN + j0a + quad * 8;
            vf[u][0] = *(const bf16x8*)(const void*)vp;
            vf[u][1] = *(const bf16x8*)(const void*)(vp + 32);
        }
        // tile B: K frags + QK
        {
            bf16x8 kf[4][2];
            #pragma unroll
            for (int t = 0; t < 4; t++) {
                const unsigned short* kp = kbb + (size_t)(j0b + t * 16 + cl) * 64 + quad * 8;
                kf[t][0] = *(const bf16x8*)(const void*)kp;
                kf[t][1] = *(const bf16x8*)(const void*)(kp + 32);
            }
            #pragma unroll
            for (int t = 0; t < 4; t++) {
                floatx4 acc = (floatx4){0.f, 0.f, 0.f, 0.f};
                acc = __builtin_amdgcn_mfma_f32_16x16x32_bf16(aq0, kf[t][0], acc, 0, 0, 0);
                acc = __builtin_amdgcn_mfma_f32_16x16x32_bf16(aq1, kf[t][1], acc, 0, 0, 0);
                #pragma unroll
                for (int r = 0; r < 4; r++) z[4 + t][r] = acc[r] * C2;
            }
        }
        #pragma unroll
        for (int u = 0; u < 4; u++) {
            const unsigned short* vp = vbb + (size_t)(u * 16 + cl) * S_LEN + j0b + quad * 8;
            vf[4 + u][0] = *(const bf16x8*)(const void*)vp;
            vf[4 + u][1] = *(const bf16x8*)(const void*)(vp + 32);
        }
        // mask: only possible on pair's second tile (first is <= nkt-5)
        if (jt + 4 == nkt - 1) {
            #pragma unroll
            for (int t = 0; t < 4; t++)
                #pragma unroll
                for (int r = 0; r < 4; r++)
                    if (j0b + t * 16 + cl > q0 + quad * 4 + r) z[4 + t][r] = -1e30f;
        }
        // one online-softmax step for all 128 keys
        float alpha[4];
        #pragma unroll
        for (int r = 0; r < 4; r++) {
            float v = fmaxf(fmaxf(fmaxf(z[0][r], z[1][r]), fmaxf(z[2][r], z[3][r])),
                            fmaxf(fmaxf(z[4][r], z[5][r]), fmaxf(z[6][r], z[7][r])));
            v = fmaxf(v, __shfl_xor(v, 1, 64));
            v = fmaxf(v, __shfl_xor(v, 2, 64));
            v = fmaxf(v, __shfl_xor(v, 4, 64));
            v = fmaxf(v, __shfl_xor(v, 8, 64));
            float mn = fmaxf(mrow[r], v);
            alpha[r] = exp2f(mrow[r] - mn);
            mrow[r] = mn;
        }
        #pragma unroll
        for (int t = 0; t < 8; t++)
            #pragma unroll
            for (int r = 0; r < 4; r++) z[t][r] = exp2f(z[t][r] - mrow[r]);
        #pragma unroll
        for (int r = 0; r < 4; r++) {
            float s = ((z[0][r] + z[1][r]) + (z[2][r] + z[3][r]))
                    + ((z[4][r] + z[5][r]) + (z[6][r] + z[7][r]));
            lrow[r] = lrow[r] * alpha[r] + s;
        }
        #pragma unroll
        for (int u = 0; u < 4; u++)
            #pragma unroll
            for (int r = 0; r < 4; r++) Oacc[u][r] *= alpha[r];
        // P strip 16x128 -> A-layout via wave-local LDS
        #pragma unroll
        for (int t = 0; t < 8; t++)
            #pragma unroll
            for (int r = 0; r < 4; r++)
                Pw[(quad * 4 + r) * PSTR + t * 16 + cl] = f2bf(z[t][r]);
        asm volatile("s_waitcnt lgkmcnt(0)" ::: "memory");
        bf16x8 ap0 = *(const bf16x8*)(const void*)(Pw + cl * PSTR + quad * 8);
        bf16x8 ap1 = *(const bf16x8*)(const void*)(Pw + cl * PSTR + 32 + quad * 8);
        bf16x8 ap2 = *(const bf16x8*)(const void*)(Pw + cl * PSTR + 64 + quad * 8);
        bf16x8 ap3 = *(const bf16x8*)(const void*)(Pw + cl * PSTR + 96 + quad * 8);
        #pragma unroll
        for (int u = 0; u < 4; u++) {
            Oacc[u] = __builtin_amdgcn_mfma_f32_16x16x32_bf16(ap0, vf[u][0], Oacc[u], 0, 0, 0);
            Oacc[u] = __builtin_amdgcn_mfma_f32_16x16x32_bf16(ap1, vf[u][1], Oacc[u], 0, 0, 0);
            Oacc[u] = __builtin_amdgcn_mfma_f32_16x16x32_bf16(ap2, vf[4 + u][0], Oacc[u], 0, 0, 0);
            Oacc[u] = __builtin_amdgcn_mfma_f32_16x16x32_bf16(ap3, vf[4 + u][1], Oacc[u], 0, 0, 0);
        }
    }
    // -------- leftover single tile (proven R4 path) --------
    if (jt < nkt) {
        const int j0 = jt * 64;
        bf16x8 kf[4][2], vf[4][2];
        #pragma unroll
        for (int t = 0; t < 4; t++) {
            const unsigned short* kp = kbb + (size_t)(j0 + t * 16 + cl) * 64 + quad * 8;
            kf[t][0] = *(const bf16x8*)(const void*)kp;
            kf[t][1] = *(const bf16x8*)(const void*)(kp + 32);
        }
        #pragma unroll
        for (int u = 0; u < 4; u++) {
            const unsigned short* vp = vbb + (size_t)(u * 16 + cl) * S_LEN + j0 + quad * 8;
            vf[u][0] = *(const bf16x8*)(const void*)vp;
            vf[u][1] = *(const bf16x8*)(const void*)(vp + 32);
        }
        float z[4][4];
        #pragma unroll
        for (int t = 0; t < 4; t++) {
            floatx4 acc = (floatx4){0.f, 0.f, 0.f, 0.f};
            acc = __builtin_amdgcn_mfma_f32_16x16x32_bf16(aq0, kf[t][0], acc, 0, 0, 0);
            acc = __builtin_amdgcn_mfma_f32_16x16x32_bf16(aq1, kf[t][1], acc, 0, 0, 0);
            #pragma unroll
            for (int r = 0; r < 4; r++) z[t][r] = acc[r] * C2;
        }
        if (jt == nkt - 1) {
            #pragma unroll
            for (int t = 0; t < 4; t++)
                #pragma unroll
                for (int r = 0; r < 4; r++)
                    if (j0 + t * 16 + cl > q0 + quad * 4 + r) z[t][r] = -1e30f;
        }
        float alpha[4];
        #pragma unroll
        for (int r = 0; r < 4; r++) {
            float v = fmaxf(fmaxf(z[0][r], z[1][r]), fmaxf(z[2][r], z[3][r]));
            v = fmaxf(v, __shfl_xor(v, 1, 64));
            v = fmaxf(v, __shfl_xor(v, 2, 64));
            v = fmaxf(v, __shfl_xor(v, 4, 64));
            v = fmaxf(v, __shfl_xor(v, 8, 64));
            float mn = fmaxf(mrow[r], v);
            alpha[r] = exp2f(mrow[r] - mn);
            mrow[r] = mn;
        }
        #pragma unroll
        for (int t = 0; t < 4; t++)
            #pragma unroll
            for (int r = 0; r < 4; r++) z[t][r] = exp2f(z[t][r] - mrow[r]);
        #pragma unroll
        for (int r = 0; r < 4; r++)
            lrow[r] = lrow[r] * alpha[r] + ((z[0][r] + z[1][r]) + (z[2][r] + z[3][r]));
        #pragma unroll
        for (int u = 0; u < 4; u++)
            #pragma unroll
            for (int r = 0; r < 4; r++) Oacc[u][r] *= alpha[r];
        #pragma unroll
        for (int t = 0; t < 4; t++)
            #pragma unroll
            for (int r = 0; r < 4; r++)
                Pw[(quad * 4 + r) * PSTR + t * 16 + cl] = f2bf(z[t][r]);
        asm volatile("s_waitcnt lgkmcnt(0)" ::: "memory");
        bf16x8 ap0 = *(const bf16x8*)(const void*)(Pw + cl * PSTR + quad * 8);
        bf16x8 ap1 = *(const bf16x8*)(const void*)(Pw + cl * PSTR + 32 + quad * 8);
        #pragma unroll
        for (int u = 0; u < 4; u++) {
            Oacc[u] = __builtin_amdgcn_mfma_f32_16x16x32_bf16(ap0, vf[u][0], Oacc[u], 0, 0, 0);
            Oacc[u] = __builtin_amdgcn_mfma_f32_16x16x32_bf16(ap1, vf[u][1], Oacc[u], 0, 0, 0);
        }
    }
    // one cross-lane l reduce
    #pragma unroll
    for (int r = 0; r < 4; r++) {
        float s = lrow[r];
        s += __shfl_xor(s, 1, 64);
        s += __shfl_xor(s, 2, 64);
        s += __shfl_xor(s, 4, 64);
        s += __shfl_xor(s, 8, 64);
        lrow[r] = s;
    }
    // publish partials + merge (proven R4 path)
    #pragma unroll
    for (int u = 0; u < 4; u++)
        #pragma unroll
        for (int r = 0; r < 4; r++)
            Op[w][quad * 4 + r][u * 16 + cl] = Oacc[u][r];
    if (cl == 0) {
        #pragma unroll
        for (int r = 0; r < 4; r++) {
            Ml[w][quad * 4 + r][0] = mrow[r];
            Ml[w][quad * 4 + r][1] = lrow[r];
        }
    }
    __syncthreads();
    {
        const int row = tid >> 4, d0 = (tid & 15) * 4;
        float m0 = Ml[0][row][0], m1 = Ml[1][row][0], m2 = Ml[2][row][0], m3 = Ml[3][row][0];
        float M = fmaxf(fmaxf(m0, m1), fmaxf(m2, m3));
        float s0 = exp2f(m0 - M), s1 = exp2f(m1 - M), s2 = exp2f(m2 - M), s3 = exp2f(m3 - M);
        float L = s0 * Ml[0][row][1] + s1 * Ml[1][row][1] + s2 * Ml[2][row][1] + s3 * Ml[3][row][1];
        float invL = 1.0f / L;
        unsigned short ov[4];
        #pragma unroll
        for (int i = 0; i < 4; i++) {
            float o = s0 * Op[0][row][d0 + i] + s1 * Op[1][row][d0 + i]
                    + s2 * Op[2][row][d0 + i] + s3 * Op[3][row][d0 + i];
            ov[i] = f2bf(o * invL);
        }
        *(uint2*)(void*)(Ob + ((size_t)b * S_LEN + q0 + row) * 64 + d0) = *(const uint2*)ov;
    }
}

// ---------------- K3: out = O @ Wo + bo via MFMA (unchanged, proven)
__global__ __launch_bounds__(256) void oproj_kernel(
    const unsigned short* __restrict__ Ob, const unsigned short* __restrict__ WoT,
    const float* __restrict__ bo, float* __restrict__ out)
{
    const int row0 = blockIdx.x * 16;
    const int tid = threadIdx.x;
    const int w = tid >> 6, lane = tid & 63, cl = lane & 15, quad = lane >> 4;
    const unsigned short* op = Ob + (size_t)(row0 + cl) * 64 + quad * 8;
    const bf16x8 a0 = *(const bf16x8*)(const void*)op;
    const bf16x8 a1 = *(const bf16x8*)(const void*)(op + 32);
    #pragma unroll 2
    for (int i = 0; i < 8; i++) {
        const int n = w * 128 + i * 16 + cl;
        const unsigned short* wp = WoT + (size_t)n * 64 + quad * 8;
        bf16x8 b0 = *(const bf16x8*)(const void*)wp;
        bf16x8 b1 = *(const bf16x8*)(const void*)(wp + 32);
        floatx4 acc = (floatx4){0.f, 0.f, 0.f, 0.f};
        acc = __builtin_amdgcn_mfma_f32_16x16x32_bf16(a0, b0, acc, 0, 0, 0);
        acc = __builtin_amdgcn_mfma_f32_16x16x32_bf16(a1, b1, acc, 0, 0, 0);
        const float bod = bo[n];
        #pragma unroll
        for (int r = 0; r < 4; r++)
            out[(size_t)(row0 + quad * 4 + r) * 512 + n] = acc[r] + bod;
    }
}

extern "C" void kernel_launch(void* const* d_in, const int* in_sizes, int n_in,
                              void* d_out, int out_size, void* d_ws, size_t ws_size,
                              hipStream_t stream) {
    const float* x  = (const float*)d_in[0];
    const float* Wq = (const float*)d_in[1];
    const float* bq = (const float*)d_in[2];
    const float* Wk = (const float*)d_in[3];
    const float* bk = (const float*)d_in[4];
    const float* Wv = (const float*)d_in[5];
    const float* bv = (const float*)d_in[6];
    const float* Wo = (const float*)d_in[7];
    const float* bo = (const float*)d_in[8];
    float* out = (float*)d_out;

    unsigned short* Qb  = (unsigned short*)d_ws;               // 2 MB
    unsigned short* Kb  = Qb + (size_t)NROWS * 64;             // 2 MB
    unsigned short* Vt  = Kb + (size_t)NROWS * 64;             // 2 MB (transposed [b][64][s])
    unsigned short* Ob  = Vt + (size_t)NROWS * 64;             // 2 MB (bf16 O, row-major)
    unsigned short* WqT = Ob + (size_t)NROWS * 64;             // 64 KB each
    unsigned short* WkT = WqT + 512 * 64;
    unsigned short* WvT = WkT + 512 * 64;
    unsigned short* WoT = WvT + 512 * 64;

    convw_kernel<<<128, 256, 0, stream>>>(Wq, Wk, Wv, Wo, WqT, WkT, WvT, WoT);
    qkv_kernel<<<dim3(3, 1024), 64, 0, stream>>>(x, WqT, WkT, WvT, bq, bk, bv, Qb, Kb, Vt);
    attn_kernel<<<1024, 256, 0, stream>>>(Qb, Kb, Vt, Ob);
    oproj_kernel<<<NROWS / 16, 256, 0, stream>>>(Ob, WoT, bo, out);
}